// Round 8
// baseline (203.699 us; speedup 1.0000x reference)
//
#include <hip/hip_runtime.h>
#include <hip/hip_bf16.h>

#define CH   16
#define HID  128
#define DIM  64
#define NVOX (4 * DIM * DIM * DIM)

typedef __attribute__((ext_vector_type(8))) short short8;
typedef __attribute__((ext_vector_type(4))) float f32x4;
typedef __attribute__((ext_vector_type(2))) float f32x2;

// zero row for OOB neighborhood reads (never written; .rodata zeros)
__device__ __align__(16) const float g_zrow[1024] = {};

__device__ __forceinline__ unsigned short f2bf(float f) {
    return __bfloat16_as_ushort(__float2bfloat16(f));   // native cvt (RNE)
}

struct V4 { f32x2 lo, hi; };
__device__ __forceinline__ V4 vload(const float* p) {
    f32x4 v = *(const f32x4*)p;
    return V4{ f32x2{v[0], v[1]}, f32x2{v[2], v[3]} };
}
__device__ __forceinline__ V4 vadd(V4 a, V4 b){ return V4{a.lo+b.lo, a.hi+b.hi}; }
__device__ __forceinline__ V4 vsub(V4 a, V4 b){ return V4{a.lo-b.lo, a.hi-b.hi}; }
__device__ __forceinline__ V4 vfma2(V4 a, V4 b){       // b + 2*a  (v_pk_fma_f32)
    const f32x2 two = {2.0f, 2.0f};
    return V4{ __builtin_elementwise_fma(two, a.lo, b.lo),
               __builtin_elementwise_fma(two, a.hi, b.hi) };
}
__device__ __forceinline__ V4 vmask(V4 a, float s){
    const f32x2 ss = {s, s};
    return V4{a.lo*ss, a.hi*ss};
}

// Swapped-operand MFMA (kappa maps verified since R3, absmax 0.03125).
// Separable perception on packed-f32; OOB rows read a zero page (branchless,
// wave-uniform pointer selects hoisted out of the tile loop).
// NO min-waves clamp (R4/R6: clamp => VGPR=64 => scratch spill catastrophe).
__global__ __launch_bounds__(256) void nca_pass1(
    const float* __restrict__ x,  const float* __restrict__ w1,
    const float* __restrict__ b1, const float* __restrict__ w2,
    const float* __restrict__ b2, const float* __restrict__ ru,
    float* __restrict__ out, float* __restrict__ alpha_new,
    float* __restrict__ pre_life)
{
    __shared__ __align__(16) unsigned short sA1[8192];  // [n][h][g][m][j] 16KB
    __shared__ __align__(16) unsigned short sA2[2048];  // [s][g][m][j]     4KB
    __shared__ __align__(16) float sb1[HID];
    __shared__ __align__(16) float sb2[CH];

    for (int t = threadIdx.x; t < 8192; t += 256) {
        const int j = t & 7, mm = (t >> 3) & 15, gg = (t >> 7) & 3,
                  hh = (t >> 9) & 1, nn = t >> 10;
        const int op  = 2 * hh + (j & 1);
        const int row = 16 * gg + 4 * (j >> 1) + op;                // kappa1
        float wv = w1[row * HID + 16 * nn + mm];
        if (op) wv *= (1.0f / 32.0f);       // fold sobel 1/32 into W1
        sA1[t] = f2bf(wv);
    }
    for (int t = threadIdx.x; t < 2048; t += 256) {
        const int j = t & 7, mm = (t >> 3) & 15, gg = (t >> 7) & 3, ss = t >> 9;
        const int kk = 32 * ss + 16 * (j >> 2) + 4 * gg + (j & 3);  // kappa2
        sA2[t] = f2bf(w2[kk * CH + mm]);
    }
    if (threadIdx.x < HID) sb1[threadIdx.x] = b1[threadIdx.x];
    if (threadIdx.x < CH)  sb2[threadIdx.x] = b2[threadIdx.x];
    __syncthreads();

    const int lane = threadIdx.x & 63;
    const int wid  = __builtin_amdgcn_readfirstlane(threadIdx.x >> 6);
    const int m = lane & 15;
    const int g = lane >> 4;

    // each wave owns one full x-row of 64 voxels (4 MFMA tiles of 16)
    const int row = blockIdx.x * 4 + wid;     // wave-uniform (SGPR)
    const int hy = row & 63;
    const int dz = (row >> 6) & 63;
    const int bb = row >> 12;
    const int rowvox = row * 64;

    const short8* pA1 = ((const short8*)sA1) + (g * 16 + m);
    const short8* pA2 = ((const short8*)sA2) + (g * 16 + m);
    const float*  pb1 = sb1 + 4 * g;
    const float*  pb2 = sb2 + 4 * g;

    // 9 wave-uniform row pointers; zero page when OOB (tile-invariant)
    const float* prow[3][3];
    #pragma unroll
    for (int i = 0; i < 3; i++) {
        const int zz = dz + i - 1;
        #pragma unroll
        for (int j = 0; j < 3; j++) {
            const int yy = hy + j - 1;
            const bool ok = ((unsigned)zz < 64u) && ((unsigned)yy < 64u);
            prow[i][j] = ok ? x + (size_t)(((bb * 64 + zz) * 64 + yy) * 64) * CH
                            : g_zrow;
        }
    }

    #pragma unroll 1
    for (int t = 0; t < 4; t++) {
        const int wx = 16 * t + m;
        const float ok0 = (wx > 0)  ? 1.0f : 0.0f;
        const float ok2 = (wx < 63) ? 1.0f : 0.0f;
        const int o1 = wx * CH + 4 * g;
        const int o0 = (wx > 0  ? wx - 1 : 0 ) * CH + 4 * g;
        const int o2 = (wx < 63 ? wx + 1 : 63) * CH + 4 * g;

        V4 zA = {}, zB = {}, zC = {}, center = {};
        float pre_max = -1e30f;

        #pragma unroll
        for (int i = 0; i < 3; i++) {
            V4 ps = {}, pda = {}, pds = {};
            #pragma unroll
            for (int j = 0; j < 3; j++) {
                const float* pr = prow[i][j];
                V4 va = vload(pr + o0);
                V4 vb = vload(pr + o1);
                V4 vc = vload(pr + o2);
                va = vmask(va, ok0);
                vc = vmask(vc, ok2);
                const V4 s = vfma2(vb, vadd(va, vc));   // va + 2vb + vc
                const V4 d = vsub(va, vc);
                pre_max = fmaxf(pre_max,
                          fmaxf(fmaxf(va.hi[1], vb.hi[1]), vc.hi[1]));
                if (j == 0)      { ps = s; pda = s; pds = d; }
                else if (j == 1) { ps = vfma2(s, ps); pds = vfma2(d, pds);
                                   if (i == 1) center = vb; }
                else             { ps = vadd(ps, s); pda = vsub(pda, s);
                                   pds = vadd(pds, d); }
            }
            if (i == 0)      { zA = ps; zB = pda; zC = pds; }
            else if (i == 1) { zB = vfma2(pda, zB); zC = vfma2(pds, zC); }
            else             { zA = vsub(zA, ps); zB = vadd(zB, pda);
                               zC = vadd(zC, pds); }
        }

        // B-frags: Y[m][kappa1(h,g,j)]; (center,zA)/(zB,zC) pairs are adjacent
        short8 a0, a1;
        a0[0] = (short)f2bf(center.lo[0]); a0[1] = (short)f2bf(zA.lo[0]);
        a0[2] = (short)f2bf(center.lo[1]); a0[3] = (short)f2bf(zA.lo[1]);
        a0[4] = (short)f2bf(center.hi[0]); a0[5] = (short)f2bf(zA.hi[0]);
        a0[6] = (short)f2bf(center.hi[1]); a0[7] = (short)f2bf(zA.hi[1]);
        a1[0] = (short)f2bf(zB.lo[0]);     a1[1] = (short)f2bf(zC.lo[0]);
        a1[2] = (short)f2bf(zB.lo[1]);     a1[3] = (short)f2bf(zC.lo[1]);
        a1[4] = (short)f2bf(zB.hi[0]);     a1[5] = (short)f2bf(zC.hi[0]);
        a1[6] = (short)f2bf(zB.hi[1]);     a1[7] = (short)f2bf(zC.hi[1]);

        // stage 1: 8 n-tiles; pack relu(H) to bf16 immediately
        short8 pbf[4];
        #pragma unroll
        for (int n = 0; n < 8; n++) {
            f32x4 h = *(const f32x4*)(pb1 + 16 * n);   // broadcast LDS read
            h = __builtin_amdgcn_mfma_f32_16x16x32_bf16(pA1[(2 * n + 0) * 64], a0, h, 0, 0, 0);
            h = __builtin_amdgcn_mfma_f32_16x16x32_bf16(pA1[(2 * n + 1) * 64], a1, h, 0, 0, 0);
            #pragma unroll
            for (int r = 0; r < 4; r++)
                pbf[n >> 1][((n & 1) << 2) + r] = (short)f2bf(fmaxf(h[r], 0.0f));
        }

        // stage 2: B-frag is the lane's own packed stage-1 outputs
        f32x4 e = *(const f32x4*)pb2;
        #pragma unroll
        for (int s = 0; s < 4; s++)
            e = __builtin_amdgcn_mfma_f32_16x16x32_bf16(pA2[s * 64], pbf[s], e, 0, 0, 0);

        // epilogue: lane (m,g) owns voxel m, channels 4g..4g+3
        const int vox = rowvox + wx;
        const float mask = (ru[vox] <= 0.5f) ? 1.0f : 0.0f;
        const float cen[4] = {center.lo[0], center.lo[1],
                              center.hi[0], center.hi[1]};
        f32x4 xn;
        #pragma unroll
        for (int r = 0; r < 4; r++) xn[r] = fmaf(e[r], mask, cen[r]);
        *(f32x4*)(out + (size_t)vox * CH + 4 * g) = xn;
        if (g == 0) {
            alpha_new[vox] = xn[3];
            pre_life[vox]  = (pre_max > 0.1f) ? 1.0f : 0.0f;
        }
    }
}

__global__ __launch_bounds__(256) void nca_pass2(
    const float* __restrict__ alpha_new, const float* __restrict__ pre_life,
    float* __restrict__ out)
{
    const int idx = blockIdx.x * 256 + threadIdx.x;
    const int wx = idx & 63;
    const int hy = (idx >> 6) & 63;
    const int dz = (idx >> 12) & 63;

    float m = -1e30f;
    #pragma unroll
    for (int i = 0; i < 3; i++) {
        const int zz = dz + i - 1;
        if ((unsigned)zz >= 64u) continue;
        #pragma unroll
        for (int j = 0; j < 3; j++) {
            const int yy = hy + j - 1;
            if ((unsigned)yy >= 64u) continue;
            #pragma unroll
            for (int k = 0; k < 3; k++) {
                const int xx = wx + k - 1;
                if ((unsigned)xx >= 64u) continue;
                m = fmaxf(m, alpha_new[idx + (i - 1) * 4096 + (j - 1) * 64 + (k - 1)]);
            }
        }
    }
    const float life = (m > 0.1f && pre_life[idx] > 0.5f) ? 1.0f : 0.0f;

    float4* p = (float4*)(out + (size_t)idx * CH);
    #pragma unroll
    for (int q = 0; q < 4; q++) {
        float4 v = p[q];
        v.x *= life; v.y *= life; v.z *= life; v.w *= life;
        p[q] = v;
    }
}

extern "C" void kernel_launch(void* const* d_in, const int* in_sizes, int n_in,
                              void* d_out, int out_size, void* d_ws, size_t ws_size,
                              hipStream_t stream) {
    const float* x  = (const float*)d_in[0];
    const float* w1 = (const float*)d_in[1];
    const float* b1 = (const float*)d_in[2];
    const float* w2 = (const float*)d_in[3];
    const float* b2 = (const float*)d_in[4];
    const float* ru = (const float*)d_in[5];
    float* out = (float*)d_out;

    float* alpha_new = (float*)d_ws;
    float* pre_life  = alpha_new + NVOX;

    // 16384 x-rows, 4 rows (waves) per block
    hipLaunchKernelGGL(nca_pass1, dim3(4096), dim3(256), 0, stream,
                       x, w1, b1, w2, b2, ru, out, alpha_new, pre_life);
    hipLaunchKernelGGL(nca_pass2, dim3(NVOX / 256), dim3(256), 0, stream,
                       alpha_new, pre_life, out);
}

// Round 9
// 180.960 us; speedup vs baseline: 1.1257x; 1.1257x over previous
//
#include <hip/hip_runtime.h>
#include <hip/hip_bf16.h>

#define CH   16
#define HID  128
#define DIM  64
#define NVOX (4 * DIM * DIM * DIM)

typedef __attribute__((ext_vector_type(8))) short short8;
typedef __attribute__((ext_vector_type(4))) float f32x4;
typedef __attribute__((ext_vector_type(2))) float f32x2;

// zero row for OOB neighborhood reads (never written; .rodata zeros)
__device__ __align__(16) const float g_zrow[1024] = {};

__device__ __forceinline__ unsigned short f2bf(float f) {
    return __bfloat16_as_ushort(__float2bfloat16(f));   // native cvt (RNE)
}

struct V4 { f32x2 lo, hi; };
__device__ __forceinline__ V4 toV4(f32x4 v) {
    return V4{ f32x2{v[0], v[1]}, f32x2{v[2], v[3]} };
}
__device__ __forceinline__ V4 vadd(V4 a, V4 b){ return V4{a.lo+b.lo, a.hi+b.hi}; }
__device__ __forceinline__ V4 vsub(V4 a, V4 b){ return V4{a.lo-b.lo, a.hi-b.hi}; }
__device__ __forceinline__ V4 vfma2(V4 a, V4 b){       // b + 2*a  (v_pk_fma_f32)
    const f32x2 two = {2.0f, 2.0f};
    return V4{ __builtin_elementwise_fma(two, a.lo, b.lo),
               __builtin_elementwise_fma(two, a.hi, b.hi) };
}
__device__ __forceinline__ V4 vmask(V4 a, float s){
    const f32x2 ss = {s, s};
    return V4{a.lo*ss, a.hi*ss};
}

// Swapped-operand MFMA (kappa maps verified since R3, absmax 0.03125).
// R9: batch ALL 27 tap loads per tile into one clause (sched_barrier pins
// them), ONE memory-latency wait per tile instead of the 9 serialized waits
// R8's min-pressure schedule produced (~7600 cyc/tile measured).
// NO min-waves clamp (R4/R6: clamp => VGPR=64 => scratch spill catastrophe).
__global__ __launch_bounds__(256) void nca_pass1(
    const float* __restrict__ x,  const float* __restrict__ w1,
    const float* __restrict__ b1, const float* __restrict__ w2,
    const float* __restrict__ b2, const float* __restrict__ ru,
    float* __restrict__ out, float* __restrict__ alpha_new,
    float* __restrict__ pre_life)
{
    __shared__ __align__(16) unsigned short sA1[8192];  // [n][h][g][m][j] 16KB
    __shared__ __align__(16) unsigned short sA2[2048];  // [s][g][m][j]     4KB
    __shared__ __align__(16) float sb1[HID];
    __shared__ __align__(16) float sb2[CH];

    for (int t = threadIdx.x; t < 8192; t += 256) {
        const int j = t & 7, mm = (t >> 3) & 15, gg = (t >> 7) & 3,
                  hh = (t >> 9) & 1, nn = t >> 10;
        const int op  = 2 * hh + (j & 1);
        const int row = 16 * gg + 4 * (j >> 1) + op;                // kappa1
        float wv = w1[row * HID + 16 * nn + mm];
        if (op) wv *= (1.0f / 32.0f);       // fold sobel 1/32 into W1
        sA1[t] = f2bf(wv);
    }
    for (int t = threadIdx.x; t < 2048; t += 256) {
        const int j = t & 7, mm = (t >> 3) & 15, gg = (t >> 7) & 3, ss = t >> 9;
        const int kk = 32 * ss + 16 * (j >> 2) + 4 * gg + (j & 3);  // kappa2
        sA2[t] = f2bf(w2[kk * CH + mm]);
    }
    if (threadIdx.x < HID) sb1[threadIdx.x] = b1[threadIdx.x];
    if (threadIdx.x < CH)  sb2[threadIdx.x] = b2[threadIdx.x];
    __syncthreads();

    const int lane = threadIdx.x & 63;
    const int wid  = __builtin_amdgcn_readfirstlane(threadIdx.x >> 6);
    const int m = lane & 15;
    const int g = lane >> 4;

    // each wave owns one full x-row of 64 voxels (4 MFMA tiles of 16)
    const int row = blockIdx.x * 4 + wid;     // wave-uniform (SGPR)
    const int hy = row & 63;
    const int dz = (row >> 6) & 63;
    const int bb = row >> 12;
    const int rowvox = row * 64;

    const short8* pA1 = ((const short8*)sA1) + (g * 16 + m);
    const short8* pA2 = ((const short8*)sA2) + (g * 16 + m);
    const float*  pb1 = sb1 + 4 * g;
    const float*  pb2 = sb2 + 4 * g;

    // 9 wave-uniform row pointers; zero page when OOB (tile-invariant)
    const float* prow[3][3];
    #pragma unroll
    for (int i = 0; i < 3; i++) {
        const int zz = dz + i - 1;
        #pragma unroll
        for (int j = 0; j < 3; j++) {
            const int yy = hy + j - 1;
            const bool ok = ((unsigned)zz < 64u) && ((unsigned)yy < 64u);
            prow[i][j] = ok ? x + (size_t)(((bb * 64 + zz) * 64 + yy) * 64) * CH
                            : g_zrow;
        }
    }

    #pragma unroll 1
    for (int t = 0; t < 4; t++) {
        const int wx = 16 * t + m;
        const float ok0 = (wx > 0)  ? 1.0f : 0.0f;
        const float ok2 = (wx < 63) ? 1.0f : 0.0f;
        const int o1 = wx * CH + 4 * g;
        const int o0 = (wx > 0  ? wx - 1 : 0 ) * CH + 4 * g;
        const int o2 = (wx < 63 ? wx + 1 : 63) * CH + 4 * g;

        const int vox = rowvox + wx;
        const float rv = ru[vox];            // hoisted into the load clause

        // ---- issue ALL 27 tap loads, pinned before the combine ----
        f32x4 L[3][3][3];
        #pragma unroll
        for (int i = 0; i < 3; i++) {
            #pragma unroll
            for (int j = 0; j < 3; j++) {
                const float* pr = prow[i][j];
                L[i][j][0] = *(const f32x4*)(pr + o0);
                L[i][j][1] = *(const f32x4*)(pr + o1);
                L[i][j][2] = *(const f32x4*)(pr + o2);
            }
        }
        __builtin_amdgcn_sched_barrier(0);   // don't re-sink loads to uses

        V4 zA = {}, zB = {}, zC = {}, center = {};
        float pre_max = -1e30f;

        #pragma unroll
        for (int i = 0; i < 3; i++) {
            V4 ps = {}, pda = {}, pds = {};
            #pragma unroll
            for (int j = 0; j < 3; j++) {
                V4 va = vmask(toV4(L[i][j][0]), ok0);
                V4 vb = toV4(L[i][j][1]);
                V4 vc = vmask(toV4(L[i][j][2]), ok2);
                const V4 s = vfma2(vb, vadd(va, vc));   // va + 2vb + vc
                const V4 d = vsub(va, vc);
                pre_max = fmaxf(pre_max,
                          fmaxf(fmaxf(va.hi[1], vb.hi[1]), vc.hi[1]));
                if (j == 0)      { ps = s; pda = s; pds = d; }
                else if (j == 1) { ps = vfma2(s, ps); pds = vfma2(d, pds);
                                   if (i == 1) center = vb; }
                else             { ps = vadd(ps, s); pda = vsub(pda, s);
                                   pds = vadd(pds, d); }
            }
            if (i == 0)      { zA = ps; zB = pda; zC = pds; }
            else if (i == 1) { zB = vfma2(pda, zB); zC = vfma2(pds, zC); }
            else             { zA = vsub(zA, ps); zB = vadd(zB, pda);
                               zC = vadd(zC, pds); }
        }

        // B-frags: Y[m][kappa1(h,g,j)]; (center,zA)/(zB,zC) pairs are adjacent
        short8 a0, a1;
        a0[0] = (short)f2bf(center.lo[0]); a0[1] = (short)f2bf(zA.lo[0]);
        a0[2] = (short)f2bf(center.lo[1]); a0[3] = (short)f2bf(zA.lo[1]);
        a0[4] = (short)f2bf(center.hi[0]); a0[5] = (short)f2bf(zA.hi[0]);
        a0[6] = (short)f2bf(center.hi[1]); a0[7] = (short)f2bf(zA.hi[1]);
        a1[0] = (short)f2bf(zB.lo[0]);     a1[1] = (short)f2bf(zC.lo[0]);
        a1[2] = (short)f2bf(zB.lo[1]);     a1[3] = (short)f2bf(zC.lo[1]);
        a1[4] = (short)f2bf(zB.hi[0]);     a1[5] = (short)f2bf(zC.hi[0]);
        a1[6] = (short)f2bf(zB.hi[1]);     a1[7] = (short)f2bf(zC.hi[1]);

        // stage 1: 8 n-tiles; pack relu(H) to bf16 immediately
        short8 pbf[4];
        #pragma unroll
        for (int n = 0; n < 8; n++) {
            f32x4 h = *(const f32x4*)(pb1 + 16 * n);   // broadcast LDS read
            h = __builtin_amdgcn_mfma_f32_16x16x32_bf16(pA1[(2 * n + 0) * 64], a0, h, 0, 0, 0);
            h = __builtin_amdgcn_mfma_f32_16x16x32_bf16(pA1[(2 * n + 1) * 64], a1, h, 0, 0, 0);
            #pragma unroll
            for (int r = 0; r < 4; r++)
                pbf[n >> 1][((n & 1) << 2) + r] = (short)f2bf(fmaxf(h[r], 0.0f));
        }

        // stage 2: B-frag is the lane's own packed stage-1 outputs
        f32x4 e = *(const f32x4*)pb2;
        #pragma unroll
        for (int s = 0; s < 4; s++)
            e = __builtin_amdgcn_mfma_f32_16x16x32_bf16(pA2[s * 64], pbf[s], e, 0, 0, 0);

        // epilogue: lane (m,g) owns voxel m, channels 4g..4g+3
        const float mask = (rv <= 0.5f) ? 1.0f : 0.0f;
        const float cen[4] = {center.lo[0], center.lo[1],
                              center.hi[0], center.hi[1]};
        f32x4 xn;
        #pragma unroll
        for (int r = 0; r < 4; r++) xn[r] = fmaf(e[r], mask, cen[r]);
        *(f32x4*)(out + (size_t)vox * CH + 4 * g) = xn;
        if (g == 0) {
            alpha_new[vox] = xn[3];
            pre_life[vox]  = (pre_max > 0.1f) ? 1.0f : 0.0f;
        }
    }
}

__global__ __launch_bounds__(256) void nca_pass2(
    const float* __restrict__ alpha_new, const float* __restrict__ pre_life,
    float* __restrict__ out)
{
    const int idx = blockIdx.x * 256 + threadIdx.x;
    const int wx = idx & 63;
    const int hy = (idx >> 6) & 63;
    const int dz = (idx >> 12) & 63;

    float m = -1e30f;
    #pragma unroll
    for (int i = 0; i < 3; i++) {
        const int zz = dz + i - 1;
        if ((unsigned)zz >= 64u) continue;
        #pragma unroll
        for (int j = 0; j < 3; j++) {
            const int yy = hy + j - 1;
            if ((unsigned)yy >= 64u) continue;
            #pragma unroll
            for (int k = 0; k < 3; k++) {
                const int xx = wx + k - 1;
                if ((unsigned)xx >= 64u) continue;
                m = fmaxf(m, alpha_new[idx + (i - 1) * 4096 + (j - 1) * 64 + (k - 1)]);
            }
        }
    }
    const float life = (m > 0.1f && pre_life[idx] > 0.5f) ? 1.0f : 0.0f;

    float4* p = (float4*)(out + (size_t)idx * CH);
    #pragma unroll
    for (int q = 0; q < 4; q++) {
        float4 v = p[q];
        v.x *= life; v.y *= life; v.z *= life; v.w *= life;
        p[q] = v;
    }
}

extern "C" void kernel_launch(void* const* d_in, const int* in_sizes, int n_in,
                              void* d_out, int out_size, void* d_ws, size_t ws_size,
                              hipStream_t stream) {
    const float* x  = (const float*)d_in[0];
    const float* w1 = (const float*)d_in[1];
    const float* b1 = (const float*)d_in[2];
    const float* w2 = (const float*)d_in[3];
    const float* b2 = (const float*)d_in[4];
    const float* ru = (const float*)d_in[5];
    float* out = (float*)d_out;

    float* alpha_new = (float*)d_ws;
    float* pre_life  = alpha_new + NVOX;

    // 16384 x-rows, 4 rows (waves) per block
    hipLaunchKernelGGL(nca_pass1, dim3(4096), dim3(256), 0, stream,
                       x, w1, b1, w2, b2, ru, out, alpha_new, pre_life);
    hipLaunchKernelGGL(nca_pass2, dim3(NVOX / 256), dim3(256), 0, stream,
                       alpha_new, pre_life, out);
}

// Round 10
// 101.291 us; speedup vs baseline: 2.0110x; 1.7865x over previous
//
#include <hip/hip_runtime.h>
#include <hip/hip_bf16.h>

#define CH   16
#define HID  128
#define DIM  64
#define NVOX (4 * DIM * DIM * DIM)

typedef __attribute__((ext_vector_type(8))) short short8;
typedef __attribute__((ext_vector_type(4))) float f32x4;
typedef __attribute__((ext_vector_type(2))) float f32x2;

// zero row for OOB neighborhood reads (never written; .rodata zeros)
__device__ __align__(16) const float g_zrow[1024] = {};

__device__ __forceinline__ unsigned short f2bf(float f) {
    return __bfloat16_as_ushort(__float2bfloat16(f));   // native cvt (RNE)
}

struct V4 { f32x2 lo, hi; };
__device__ __forceinline__ V4 toV4(f32x4 v) {
    return V4{ f32x2{v[0], v[1]}, f32x2{v[2], v[3]} };
}
__device__ __forceinline__ V4 vadd(V4 a, V4 b){ return V4{a.lo+b.lo, a.hi+b.hi}; }
__device__ __forceinline__ V4 vsub(V4 a, V4 b){ return V4{a.lo-b.lo, a.hi-b.hi}; }
__device__ __forceinline__ V4 vfma2(V4 a, V4 b){       // b + 2*a  (v_pk_fma_f32)
    const f32x2 two = {2.0f, 2.0f};
    return V4{ __builtin_elementwise_fma(two, a.lo, b.lo),
               __builtin_elementwise_fma(two, a.hi, b.hi) };
}
__device__ __forceinline__ V4 vmask(V4 a, float s){
    const f32x2 ss = {s, s};
    return V4{a.lo*ss, a.hi*ss};
}

struct Plane { V4 ps, pda, pds, vb; float pmax; };

// R10: rolling-window over z. Wave owns fixed (b,y,16-voxel x-tile), walks a
// 16-deep z-chunk keeping a 3-plane ring of separable partials. Each step:
// 9 loads (one plane) instead of 27, 1/3 the conv VALU. Swapped-operand MFMA
// (kappa maps verified since R3). NO min-waves clamp (R4/R6 spill disaster).
__global__ __launch_bounds__(256) void nca_pass1(
    const float* __restrict__ x,  const float* __restrict__ w1,
    const float* __restrict__ b1, const float* __restrict__ w2,
    const float* __restrict__ b2, const float* __restrict__ ru,
    float* __restrict__ out, float* __restrict__ alpha_new,
    float* __restrict__ pre_life)
{
    __shared__ __align__(16) unsigned short sA1[8192];  // [n][h][g][m][j] 16KB
    __shared__ __align__(16) unsigned short sA2[2048];  // [s][g][m][j]     4KB
    __shared__ __align__(16) float sb1[HID];
    __shared__ __align__(16) float sb2[CH];

    for (int t = threadIdx.x; t < 8192; t += 256) {
        const int j = t & 7, mm = (t >> 3) & 15, gg = (t >> 7) & 3,
                  hh = (t >> 9) & 1, nn = t >> 10;
        const int op  = 2 * hh + (j & 1);
        const int row = 16 * gg + 4 * (j >> 1) + op;                // kappa1
        float wv = w1[row * HID + 16 * nn + mm];
        if (op) wv *= (1.0f / 32.0f);       // fold sobel 1/32 into W1
        sA1[t] = f2bf(wv);
    }
    for (int t = threadIdx.x; t < 2048; t += 256) {
        const int j = t & 7, mm = (t >> 3) & 15, gg = (t >> 7) & 3, ss = t >> 9;
        const int kk = 32 * ss + 16 * (j >> 2) + 4 * gg + (j & 3);  // kappa2
        sA2[t] = f2bf(w2[kk * CH + mm]);
    }
    if (threadIdx.x < HID) sb1[threadIdx.x] = b1[threadIdx.x];
    if (threadIdx.x < CH)  sb2[threadIdx.x] = b2[threadIdx.x];
    __syncthreads();

    const int lane = threadIdx.x & 63;
    const int wid  = __builtin_amdgcn_readfirstlane(threadIdx.x >> 6);
    const int m = lane & 15;
    const int g = lane >> 4;

    // decode: blockIdx -> (b, y, z-chunk); wave id -> x-tile
    const int zc = blockIdx.x & 3;
    const int y  = (blockIdx.x >> 2) & 63;
    const int b  = blockIdx.x >> 8;
    const int z0 = zc << 4;

    const short8* pA1 = ((const short8*)sA1) + (g * 16 + m);
    const short8* pA2 = ((const short8*)sA2) + (g * 16 + m);
    const float*  pb1 = sb1 + 4 * g;
    const float*  pb2 = sb2 + 4 * g;

    const int wx = 16 * wid + m;
    const float ok0 = (wx > 0)  ? 1.0f : 0.0f;
    const float ok2 = (wx < 63) ? 1.0f : 0.0f;
    const int o1 = wx * CH + 4 * g;
    const int o0 = (wx > 0  ? wx - 1 : 0 ) * CH + 4 * g;
    const int o2 = (wx < 63 ? wx + 1 : 63) * CH + 4 * g;

    f32x4 L[3][3];          // one plane of taps: [row y-1|y|y+1][x-tap]
    Plane PA{}, PB{}, PC{};

#define LOADP(zz) do {                                                        \
    const bool zok = ((unsigned)(zz)) < 64u;                                  \
    const float* bp = x + ((size_t)(b * 64 + (zz))) * 65536;                  \
    const float* r0 = (zok && y > 0)  ? bp + (size_t)(y - 1) * 1024 : g_zrow; \
    const float* r1 =  zok            ? bp + (size_t)y * 1024       : g_zrow; \
    const float* r2 = (zok && y < 63) ? bp + (size_t)(y + 1) * 1024 : g_zrow; \
    L[0][0] = *(const f32x4*)(r0 + o0); L[0][1] = *(const f32x4*)(r0 + o1);   \
    L[0][2] = *(const f32x4*)(r0 + o2);                                       \
    L[1][0] = *(const f32x4*)(r1 + o0); L[1][1] = *(const f32x4*)(r1 + o1);   \
    L[1][2] = *(const f32x4*)(r1 + o2);                                       \
    L[2][0] = *(const f32x4*)(r2 + o0); L[2][1] = *(const f32x4*)(r2 + o1);   \
    L[2][2] = *(const f32x4*)(r2 + o2);                                       \
} while (0)

#define PARTIALS(P) do {                                                      \
    V4 s0, s1, s2, d0, d1, d2; float pm;                                      \
    { V4 va = vmask(toV4(L[0][0]), ok0), vb = toV4(L[0][1]),                  \
         vc = vmask(toV4(L[0][2]), ok2);                                      \
      s0 = vfma2(vb, vadd(va, vc)); d0 = vsub(va, vc);                        \
      pm = fmaxf(fmaxf(va.hi[1], vb.hi[1]), vc.hi[1]); }                      \
    { V4 va = vmask(toV4(L[1][0]), ok0), vb = toV4(L[1][1]),                  \
         vc = vmask(toV4(L[1][2]), ok2);                                      \
      s1 = vfma2(vb, vadd(va, vc)); d1 = vsub(va, vc);                        \
      pm = fmaxf(pm, fmaxf(fmaxf(va.hi[1], vb.hi[1]), vc.hi[1]));             \
      (P).vb = vb; }                                                          \
    { V4 va = vmask(toV4(L[2][0]), ok0), vb = toV4(L[2][1]),                  \
         vc = vmask(toV4(L[2][2]), ok2);                                      \
      s2 = vfma2(vb, vadd(va, vc)); d2 = vsub(va, vc);                        \
      pm = fmaxf(pm, fmaxf(fmaxf(va.hi[1], vb.hi[1]), vc.hi[1])); }           \
    (P).ps  = vfma2(s1, vadd(s0, s2));                                        \
    (P).pda = vsub(s0, s2);                                                   \
    (P).pds = vfma2(d1, vadd(d0, d2));                                        \
    (P).pmax = pm;                                                            \
} while (0)

#define STEP(Pm1, P0, Pp1, n) do {                                            \
    PARTIALS(Pp1);                       /* consumes loads issued last step */\
    LOADP(z0 + (n) + 2);                 /* issue next plane's 9 loads */     \
    const int zq = (z0 + (n) + 1 > 63) ? 63 : (z0 + (n) + 1);                 \
    const float rv_next = ru[((b * 64 + zq) * 64 + y) * 64 + wx];             \
    __builtin_amdgcn_sched_barrier(0);   /* pin loads above the compute */    \
    V4 zA = vsub((Pm1).ps, (Pp1).ps);                                         \
    V4 zB = vfma2((P0).pda, vadd((Pm1).pda, (Pp1).pda));                      \
    V4 zC = vfma2((P0).pds, vadd((Pm1).pds, (Pp1).pds));                      \
    V4 center = (P0).vb;                                                      \
    const float pre_max = fmaxf(fmaxf((Pm1).pmax, (P0).pmax), (Pp1).pmax);    \
    short8 a0, a1;                                                            \
    a0[0] = (short)f2bf(center.lo[0]); a0[1] = (short)f2bf(zA.lo[0]);         \
    a0[2] = (short)f2bf(center.lo[1]); a0[3] = (short)f2bf(zA.lo[1]);         \
    a0[4] = (short)f2bf(center.hi[0]); a0[5] = (short)f2bf(zA.hi[0]);         \
    a0[6] = (short)f2bf(center.hi[1]); a0[7] = (short)f2bf(zA.hi[1]);         \
    a1[0] = (short)f2bf(zB.lo[0]);     a1[1] = (short)f2bf(zC.lo[0]);         \
    a1[2] = (short)f2bf(zB.lo[1]);     a1[3] = (short)f2bf(zC.lo[1]);         \
    a1[4] = (short)f2bf(zB.hi[0]);     a1[5] = (short)f2bf(zC.hi[0]);         \
    a1[6] = (short)f2bf(zB.hi[1]);     a1[7] = (short)f2bf(zC.hi[1]);         \
    short8 pbf[4];                                                            \
    _Pragma("unroll")                                                         \
    for (int nn = 0; nn < 8; nn++) {                                          \
        f32x4 h = *(const f32x4*)(pb1 + 16 * nn);                             \
        h = __builtin_amdgcn_mfma_f32_16x16x32_bf16(pA1[(2*nn+0)*64], a0, h, 0, 0, 0); \
        h = __builtin_amdgcn_mfma_f32_16x16x32_bf16(pA1[(2*nn+1)*64], a1, h, 0, 0, 0); \
        _Pragma("unroll")                                                     \
        for (int r = 0; r < 4; r++)                                           \
            pbf[nn >> 1][((nn & 1) << 2) + r] = (short)f2bf(fmaxf(h[r], 0.0f)); \
    }                                                                         \
    f32x4 e = *(const f32x4*)pb2;                                             \
    _Pragma("unroll")                                                         \
    for (int s = 0; s < 4; s++)                                               \
        e = __builtin_amdgcn_mfma_f32_16x16x32_bf16(pA2[s * 64], pbf[s], e, 0, 0, 0); \
    const int vox = ((b * 64 + (z0 + (n))) * 64 + y) * 64 + wx;               \
    const float mask2 = (rv_cur <= 0.5f) ? 1.0f : 0.0f;                       \
    f32x4 xn;                                                                 \
    xn[0] = fmaf(e[0], mask2, center.lo[0]);                                  \
    xn[1] = fmaf(e[1], mask2, center.lo[1]);                                  \
    xn[2] = fmaf(e[2], mask2, center.hi[0]);                                  \
    xn[3] = fmaf(e[3], mask2, center.hi[1]);                                  \
    *(f32x4*)(out + (size_t)vox * CH + 4 * g) = xn;                           \
    if (g == 0) {                                                             \
        alpha_new[vox] = xn[3];                                               \
        pre_life[vox]  = (pre_max > 0.1f) ? 1.0f : 0.0f;                      \
    }                                                                         \
    rv_cur = rv_next;                                                         \
} while (0)

    // warmup: partials for planes z0-1, z0; loads for z0+1 in flight
    LOADP(z0 - 1);
    PARTIALS(PA);
    LOADP(z0);
    PARTIALS(PB);
    LOADP(z0 + 1);
    float rv_cur = ru[((b * 64 + z0) * 64 + y) * 64 + wx];

    STEP(PA, PB, PC, 0);
    STEP(PB, PC, PA, 1);
    STEP(PC, PA, PB, 2);
    STEP(PA, PB, PC, 3);
    STEP(PB, PC, PA, 4);
    STEP(PC, PA, PB, 5);
    STEP(PA, PB, PC, 6);
    STEP(PB, PC, PA, 7);
    STEP(PC, PA, PB, 8);
    STEP(PA, PB, PC, 9);
    STEP(PB, PC, PA, 10);
    STEP(PC, PA, PB, 11);
    STEP(PA, PB, PC, 12);
    STEP(PB, PC, PA, 13);
    STEP(PC, PA, PB, 14);
    STEP(PA, PB, PC, 15);

#undef STEP
#undef PARTIALS
#undef LOADP
}

__global__ __launch_bounds__(256) void nca_pass2(
    const float* __restrict__ alpha_new, const float* __restrict__ pre_life,
    float* __restrict__ out)
{
    const int idx = blockIdx.x * 256 + threadIdx.x;
    const int wx = idx & 63;
    const int hy = (idx >> 6) & 63;
    const int dz = (idx >> 12) & 63;

    float m = -1e30f;
    #pragma unroll
    for (int i = 0; i < 3; i++) {
        const int zz = dz + i - 1;
        if ((unsigned)zz >= 64u) continue;
        #pragma unroll
        for (int j = 0; j < 3; j++) {
            const int yy = hy + j - 1;
            if ((unsigned)yy >= 64u) continue;
            #pragma unroll
            for (int k = 0; k < 3; k++) {
                const int xx = wx + k - 1;
                if ((unsigned)xx >= 64u) continue;
                m = fmaxf(m, alpha_new[idx + (i - 1) * 4096 + (j - 1) * 64 + (k - 1)]);
            }
        }
    }
    const float life = (m > 0.1f && pre_life[idx] > 0.5f) ? 1.0f : 0.0f;

    float4* p = (float4*)(out + (size_t)idx * CH);
    #pragma unroll
    for (int q = 0; q < 4; q++) {
        float4 v = p[q];
        v.x *= life; v.y *= life; v.z *= life; v.w *= life;
        p[q] = v;
    }
}

extern "C" void kernel_launch(void* const* d_in, const int* in_sizes, int n_in,
                              void* d_out, int out_size, void* d_ws, size_t ws_size,
                              hipStream_t stream) {
    const float* x  = (const float*)d_in[0];
    const float* w1 = (const float*)d_in[1];
    const float* b1 = (const float*)d_in[2];
    const float* w2 = (const float*)d_in[3];
    const float* b2 = (const float*)d_in[4];
    const float* ru = (const float*)d_in[5];
    float* out = (float*)d_out;

    float* alpha_new = (float*)d_ws;
    float* pre_life  = alpha_new + NVOX;

    // 1024 blocks: (b, y, z-chunk); 4 waves/block = 4 x-tiles of the y-row
    hipLaunchKernelGGL(nca_pass1, dim3(1024), dim3(256), 0, stream,
                       x, w1, b1, w2, b2, ru, out, alpha_new, pre_life);
    hipLaunchKernelGGL(nca_pass2, dim3(NVOX / 256), dim3(256), 0, stream,
                       alpha_new, pre_life, out);
}